// Round 2
// baseline (178.143 us; speedup 1.0000x reference)
//
#include <hip/hip_runtime.h>
#include <math.h>

// Shapes fixed by setup_inputs(): bs=2, m=16, v=16, L=40320, P=32, beta=1
#define BS 2
#define M 16
#define V 16
#define NROWB 136           // per-batch rows: 16 target + 120 i<j pairs
#define NROWS 272           // BS * NROWB
#define PMASK 32
#define NPB 315             // pb blocks per batch (L = NPB*CH*64)
#define CH 2                // l-chunks per block
#define NE 8704             // NROWS*PMASK output elements
#define PBSTRIDE 8704       // floats per pb partial slice (2*136*32)

typedef __attribute__((ext_vector_type(8))) short bf16x8;
typedef __attribute__((ext_vector_type(4))) float f32x4;
typedef __attribute__((ext_vector_type(4))) unsigned int u32x4;

static __device__ __forceinline__ unsigned short f2bf(float x) {
    unsigned int u = __float_as_uint(x);
    unsigned int r = (u + 0x7FFFu + ((u >> 16) & 1u)) >> 16;
    return (unsigned short)r;
}

// -------- global->LDS DMA stage: 64 rows (16 i x 4 v) x 64 l f32 = 16 KB ---
static __device__ __forceinline__ void k1_stage(
    const float* __restrict__ preds, float* __restrict__ dst,
    int b, int v0, int l0, int L, int lane, int wave)
{
#pragma unroll
    for (int n = 0; n < 4; ++n) {
        int r0 = wave * 16 + n * 4;               // wave-uniform LDS row group
        int r = r0 + (lane >> 4);                 // this lane's row
        int grow = b * 256 + (r >> 2) * 16 + v0 + (r & 3);
        const float* g = preds + (size_t)grow * L + l0 + (lane & 15) * 4;
        __builtin_amdgcn_global_load_lds(
            (const __attribute__((address_space(1))) unsigned int*)g,
            (__attribute__((address_space(3))) unsigned int*)(dst + r0 * 64),
            16, 0, 0);
    }
}

// -------- per-v-quad pair/target accumulation (unchanged math) -------------
template<int W>
static __device__ __forceinline__ void k1_chunk(
    const float* __restrict__ xsb,                // 64 rows x 64 f32, r=i*4+vc
    const float* __restrict__ targ,               // 16 raw targets (W==0 only)
    const float* __restrict__ scl,                // scale[16]
    float wl,                                     // weights[l] for this lane
    int v0, int lane, float* __restrict__ acc)
{
    const int base = (W == 0) ? 0 : 34 * W - 16;  // first pair idx
    const int npair = (W == 0) ? 18 : 34;
    const int aoff = (W == 0) ? 16 : 0;

#pragma unroll
    for (int vc = 0; vc < 4; ++vc) {
        const int v = v0 + vc;                    // compile-time after unroll
        float s = scl[v] * wl;
        float x[M];
#pragma unroll
        for (int i = 0; i < M; ++i)
            x[i] = xsb[(i * 4 + vc) * 64 + lane] * s;
        if (W == 0) {
            float y = targ[v] * s;
#pragma unroll
            for (int i = 0; i < M; ++i) {
                float d = x[i] - y;
                acc[i] = fmaf(d, d, acc[i]);
            }
        }
        int k = 0;
#pragma unroll
        for (int i = 0; i < M; ++i) {
#pragma unroll
            for (int j = i + 1; j < M; ++j) {
                if (k >= base && k < base + npair) {
                    float d = x[i] - x[j];
                    acc[aoff + k - base] = fmaf(d, d, acc[aoff + k - base]);
                }
                ++k;
            }
        }
    }
}

// -------- Fused kernel: pair-sums + LDS transpose + mask-MFMA --------------
// Block (pb, b): chunks l0 = (pb + 315*c)*64, c=0,1.  Per chunk: stage 4
// v-quads (double-buffered DMA), acc[34]/lane; f2bf -> swizzled S_lds
// [144 rows][64 l] bf16; MFMA 9 row-tiles x 2 ksteps x 2 p-tiles against
// mask B-frags converted in-register (masks are exact 0/1 -> truncation
// exact).  f32 partial D2 [pb][b][136][32] accumulated over both chunks.
// LDS = 32K xs + 18K sld = 50 KB -> 3 blocks/CU.  launch_bounds(256,2):
// min_waves MUST stay 2 (R8: 4 spills acc[] to scratch).
__global__ __launch_bounds__(256, 2)
void k1_fused(const float* __restrict__ preds, const float* __restrict__ target,
              const float* __restrict__ weights, const float* __restrict__ scale,
              const float* __restrict__ masks, float* __restrict__ partial,
              float* __restrict__ out, int L)
{
    __shared__ float xs[2][4096];                 // 2 x 16 KB DMA buffers
    __shared__ unsigned short sld[144 * 64];      // 18 KB bf16 S tile

    const int t = (int)threadIdx.x;
    const int lane = t & 63, wave = t >> 6;
    const int pb = (int)blockIdx.x;
    const int b  = (int)blockIdx.y;

    if (pb == 0 && b == 0 && t == 0) out[0] = 0.0f;   // k3 atomics ordered after

    // pad rows 136..143 = 0 once (tile 8's upper half; never rewritten)
    ((unsigned int*)sld)[136 * 32 + t] = 0;

    k1_stage(preds, &xs[0][0], b, 0, pb * 64, L, lane, wave);

    // prologue scalars (chunk 0); chunk 1 reloads at its vq==0
    float scl[V];
#pragma unroll
    for (int v = 0; v < V; ++v) scl[v] = scale[v];
    float wl = weights[pb * 64 + lane];
    float targ[V];
    if (wave == 0) {
#pragma unroll
        for (int v = 0; v < V; ++v)
            targ[v] = target[(size_t)(b * V + v) * L + pb * 64 + lane];
    }

    const int ntile = (wave == 3) ? 3 : 2;        // wave3 also owns tile 8
    f32x4 pacc[3][2];
#pragma unroll
    for (int ti = 0; ti < 3; ++ti)
#pragma unroll
        for (int pt = 0; pt < 2; ++pt)
            pacc[ti][pt] = (f32x4){0.f, 0.f, 0.f, 0.f};

    float acc[34];
#pragma unroll
    for (int r = 0; r < 34; ++r) acc[r] = 0.0f;

#pragma unroll
    for (int c = 0; c < CH; ++c) {
        const int l0 = (pb + NPB * c) * 64;
#pragma unroll
        for (int vq = 0; vq < 4; ++vq) {
            const int s = c * 4 + vq;
            __syncthreads();                      // DMA(s) landed; xs[(s+1)&1] free
            if (s + 1 < 4 * CH) {                 // DMA(s+1) flies over compute(s)
                const int ns = s + 1;
                k1_stage(preds, &xs[ns & 1][0], b, (ns & 3) * 4,
                         (pb + NPB * (ns >> 2)) * 64, L, lane, wave);
            }
            if (c > 0 && vq == 0) {               // chunk-1 scalars + acc reset
                wl = weights[l0 + lane];
                if (wave == 0) {
#pragma unroll
                    for (int v = 0; v < V; ++v)
                        targ[v] = target[(size_t)(b * V + v) * L + l0 + lane];
                }
#pragma unroll
                for (int r = 0; r < 34; ++r) acc[r] = 0.0f;
            }
            const float* xsb = &xs[s & 1][0];
            switch (wave) {
                case 0: k1_chunk<0>(xsb, targ, scl, wl, vq * 4, lane, acc); break;
                case 1: k1_chunk<1>(xsb, targ, scl, wl, vq * 4, lane, acc); break;
                case 2: k1_chunk<2>(xsb, targ, scl, wl, vq * 4, lane, acc); break;
                default: k1_chunk<3>(xsb, targ, scl, wl, vq * 4, lane, acc); break;
            }
        }

        // ---- acc -> S_lds, XOR-swizzled (row stride 128 B would be a
        // 16-way bank conflict on the b128 fragment reads; bits[3:5] of the
        // short index XOR'd with row&7 spreads rows over 8 slots, 2-way=free)
#pragma unroll
        for (int r = 0; r < 34; ++r) {
            const int R = 34 * wave + r;
            sld[R * 64 + (lane ^ ((R & 7) << 3))] = f2bf(acc[r]);
        }
        __syncthreads();                          // cross-wave: tiles mix writers

        // ---- MFMA: pacc += S_tile x mask^T (layouts mirrored from old k2)
#pragma unroll
        for (int ks = 0; ks < 2; ++ks) {
            bf16x8 bfr[2];
#pragma unroll
            for (int pt = 0; pt < 2; ++pt) {
                // B-frag: p = pt*16+(lane&15), 8 contig l; 0/1 -> bf16 = hi16
                const float* mp = masks + (size_t)(pt * 16 + (lane & 15)) * L
                                + l0 + ks * 32 + (lane >> 4) * 8;
                u32x4 m0 = *(const u32x4*)mp;
                u32x4 m1 = *(const u32x4*)(mp + 4);
                union { unsigned int u[4]; bf16x8 v; } bb;
                bb.u[0] = __builtin_amdgcn_perm(m0.y, m0.x, 0x07060302);
                bb.u[1] = __builtin_amdgcn_perm(m0.w, m0.z, 0x07060302);
                bb.u[2] = __builtin_amdgcn_perm(m1.y, m1.x, 0x07060302);
                bb.u[3] = __builtin_amdgcn_perm(m1.w, m1.z, 0x07060302);
                bfr[pt] = bb.v;
            }
#pragma unroll
            for (int ti = 0; ti < 3; ++ti) {
                if (ti >= ntile) continue;        // wave-uniform
                const int tile = (ti == 2) ? 8 : (wave + ti * 4);
                const bf16x8 a = *(const bf16x8*)&sld[
                    (tile * 16 + (lane & 15)) * 64 +
                    ((ks * 32 + (lane >> 4) * 8) ^ ((lane & 7) << 3))];
                pacc[ti][0] = __builtin_amdgcn_mfma_f32_16x16x32_bf16(
                    a, bfr[0], pacc[ti][0], 0, 0, 0);
                pacc[ti][1] = __builtin_amdgcn_mfma_f32_16x16x32_bf16(
                    a, bfr[1], pacc[ti][1], 0, 0, 0);
            }
        }
        // no extra barrier: next chunk's first sld write sits 4 barriers away
    }

    // ---- store partial D2 for this (pb, b): [136][32] f32 -----------------
    float* P = partial + (size_t)(pb * 2 + b) * (NROWB * PMASK);
#pragma unroll
    for (int ti = 0; ti < 3; ++ti) {
        if (ti >= ntile) continue;
        const int tile = (ti == 2) ? 8 : (wave + ti * 4);
#pragma unroll
        for (int pt = 0; pt < 2; ++pt)
#pragma unroll
            for (int reg = 0; reg < 4; ++reg) {
                const int row = tile * 16 + (lane >> 4) * 4 + reg;
                if (row < NROWB)                  // drop pad rows 136..143
                    P[row * 32 + pt * 16 + (lane & 15)] = pacc[ti][pt][reg];
            }
    }
}

// -------- k3: pb-sum (coalesced: idx = e + pb*8704), sqrt, reduce, atomic --
__global__ __launch_bounds__(256, 2)
void k3_finalize(const float* __restrict__ P, const int* __restrict__ beta_p,
                 float* __restrict__ out)
{
    const int t = (int)threadIdx.x;
    const int e = (int)blockIdx.x * 256 + t;      // 0..8703 = b*4352+row*32+p

    float a0 = 0.f, a1 = 0.f, a2 = 0.f, a3 = 0.f, a4 = 0.f;
    const float* p = P + e;
    for (int q = 0; q < NPB; q += 5) {            // 315 = 63*5, q = pb
        a0 += p[(size_t)(q    ) * PBSTRIDE];
        a1 += p[(size_t)(q + 1) * PBSTRIDE];
        a2 += p[(size_t)(q + 2) * PBSTRIDE];
        a3 += p[(size_t)(q + 3) * PBSTRIDE];
        a4 += p[(size_t)(q + 4) * PBSTRIDE];
    }
    float d2 = fmaxf(((a0 + a1) + (a2 + a3)) + a4, 0.0f);
    float beta = (float)beta_p[0];
    float d = (beta == 1.0f) ? sqrtf(d2) : powf(d2, 0.5f * beta);

    const float wa = 1.0f / (float)(BS * M);
    const float wb = -1.0f / (float)(BS * M * (M - 1));
    const int row_g = e >> 5;
    const int local = row_g % NROWB;
    float sum = ((local < M) ? wa : wb) * d;

    const int lane = t & 63, wv = t >> 6;
#pragma unroll
    for (int off = 32; off > 0; off >>= 1)
        sum += __shfl_down(sum, off, 64);
    __shared__ float red[4];
    if (lane == 0) red[wv] = sum;
    __syncthreads();
    if (t == 0)
        atomicAdd(out, red[0] + red[1] + red[2] + red[3]);
}

extern "C" void kernel_launch(void* const* d_in, const int* in_sizes, int n_in,
                              void* d_out, int out_size, void* d_ws, size_t ws_size,
                              hipStream_t stream)
{
    const float* preds   = (const float*)d_in[0];
    const float* target  = (const float*)d_in[1];
    const float* weights = (const float*)d_in[2];
    const float* scale   = (const float*)d_in[3];
    const float* masks   = (const float*)d_in[4];
    const int*   beta    = (const int*)d_in[5];
    float* out = (float*)d_out;

    int L = in_sizes[2];   // 40320 = NPB*CH*64

    float* partial = (float*)d_ws;                // 315*2*136*32 f32 = 11 MB

    dim3 g1(NPB, BS);                             // 315 x 2
    k1_fused<<<g1, 256, 0, stream>>>(preds, target, weights, scale, masks,
                                     partial, out, L);

    k3_finalize<<<NE / 256, 256, 0, stream>>>(partial, beta, out);
}

// Round 3
// 152.470 us; speedup vs baseline: 1.1684x; 1.1684x over previous
//
#include <hip/hip_runtime.h>
#include <math.h>

// Shapes fixed by setup_inputs(): bs=2, m=16, v=16, L=40320, P=32, beta=1
#define BS 2
#define M 16
#define V 16
#define NROWB 136           // per-batch rows: 16 target + 120 i<j pairs
#define NROWS 272           // BS * NROWB
#define PMASK 32
#define NPB 630             // l-chunks = blocks per batch (L = NPB*64)
#define NE 8704             // NROWS*PMASK output elements
#define PBSTRIDE 8704       // floats per pb step in partial (2*136*32)
#define SPLIT 30            // k3a pb-groups
#define QPB 21              // pb per group (630 = 30*21)

typedef __attribute__((ext_vector_type(8))) short bf16x8;
typedef __attribute__((ext_vector_type(4))) float f32x4;
typedef __attribute__((ext_vector_type(4))) unsigned int u32x4;

static __device__ __forceinline__ unsigned short f2bf(float x) {
    unsigned int u = __float_as_uint(x);
    unsigned int r = (u + 0x7FFFu + ((u >> 16) & 1u)) >> 16;
    return (unsigned short)r;
}

// -------- global->LDS DMA stage: 32 rows (16 i x 2 v) x 64 l f32 = 8 KB ----
// Row r = i*2 + vc  (vc = v - v0, v0 = 2*stage).  Per wave: 2 instrs x 4 rows.
static __device__ __forceinline__ void k1_stage(
    const float* __restrict__ preds, float* __restrict__ dst,
    int b, int v0, int l0, int L, int lane, int wave)
{
#pragma unroll
    for (int n = 0; n < 2; ++n) {
        int r0 = wave * 8 + n * 4;                // wave-uniform LDS row group
        int r = r0 + (lane >> 4);                 // this lane's row
        int grow = b * 256 + (r >> 1) * 16 + v0 + (r & 1);
        const float* g = preds + (size_t)grow * L + l0 + (lane & 15) * 4;
        __builtin_amdgcn_global_load_lds(
            (const __attribute__((address_space(1))) unsigned int*)g,
            (__attribute__((address_space(3))) unsigned int*)(dst + r0 * 64),
            16, 0, 0);
    }
}

// -------- per-2v-stage pair/target accumulation (same math, stride-2 rows) -
template<int W>
static __device__ __forceinline__ void k1_chunk(
    const float* __restrict__ xsb,                // 32 rows x 64 f32, r=i*2+vc
    const float* __restrict__ targ,               // 16 raw targets (W==0 only)
    const float* __restrict__ scl,                // scale[16]
    float wl,                                     // weights[l] for this lane
    int v0, int lane, float* __restrict__ acc)
{
    const int base = (W == 0) ? 0 : 34 * W - 16;  // first pair idx
    const int npair = (W == 0) ? 18 : 34;
    const int aoff = (W == 0) ? 16 : 0;

#pragma unroll
    for (int vc = 0; vc < 2; ++vc) {
        const int v = v0 + vc;                    // compile-time after unroll
        float s = scl[v] * wl;
        float x[M];
#pragma unroll
        for (int i = 0; i < M; ++i)
            x[i] = xsb[(i * 2 + vc) * 64 + lane] * s;
        if (W == 0) {
            float y = targ[v] * s;
#pragma unroll
            for (int i = 0; i < M; ++i) {
                float d = x[i] - y;
                acc[i] = fmaf(d, d, acc[i]);
            }
        }
        int k = 0;
#pragma unroll
        for (int i = 0; i < M; ++i) {
#pragma unroll
            for (int j = i + 1; j < M; ++j) {
                if (k >= base && k < base + npair) {
                    float d = x[i] - x[j];
                    acc[aoff + k - base] = fmaf(d, d, acc[aoff + k - base]);
                }
                ++k;
            }
        }
    }
}

// -------- Fused kernel: pair-sums + LDS transpose + mask-MFMA --------------
// Block (pb, b) owns ONE 64-l chunk (l0 = pb*64).  8 stages of 2 v's each,
// 8 KB DMA double-buffered; acc[34]/lane; f2bf -> swizzled S_lds
// [144 rows][64 l] bf16; MFMA 9 row-tiles x 2 ksteps x 2 p-tiles against
// mask B-frags converted in-register (masks exact 0/1 -> truncation exact).
// f32 partial D2 [pb][b][136][32].  LDS = 16K xs + 18K sld = 34 KB ->
// 4 blocks/CU (vs R2's 3-cap/2.46-actual: the measured residency fix).
// launch_bounds(256,2): min_waves MUST stay 2 (R8: 4 spills acc[]).
__global__ __launch_bounds__(256, 2)
void k1_fused(const float* __restrict__ preds, const float* __restrict__ target,
              const float* __restrict__ weights, const float* __restrict__ scale,
              const float* __restrict__ masks, float* __restrict__ partial,
              float* __restrict__ out, int L)
{
    __shared__ float xs[2][2048];                 // 2 x 8 KB DMA buffers
    __shared__ unsigned short sld[144 * 64];      // 18 KB bf16 S tile

    const int t = (int)threadIdx.x;
    const int lane = t & 63, wave = t >> 6;
    const int pb = (int)blockIdx.x;
    const int b  = (int)blockIdx.y;
    const int l0 = pb * 64;

    if (pb == 0 && b == 0 && t == 0) out[0] = 0.0f;   // k3b atomics ordered after

    // pad rows 136..143 = 0 once (tile 8's upper half; never rewritten)
    ((unsigned int*)sld)[136 * 32 + t] = 0;

    k1_stage(preds, &xs[0][0], b, 0, l0, L, lane, wave);

    // prologue: ALL scalar global loads (no extra vmcnt waits in the loop)
    float scl[V];
#pragma unroll
    for (int v = 0; v < V; ++v) scl[v] = scale[v];
    float wl = weights[l0 + lane];
    float targ[V];
    if (wave == 0) {
#pragma unroll
        for (int v = 0; v < V; ++v)
            targ[v] = target[(size_t)(b * V + v) * L + l0 + lane];
    }

    float acc[34];
#pragma unroll
    for (int r = 0; r < 34; ++r) acc[r] = 0.0f;

#pragma unroll
    for (int s = 0; s < 8; ++s) {
        __syncthreads();                          // DMA(s) landed; xs[(s+1)&1] free
        if (s < 7)                                // DMA(s+1) flies over compute(s)
            k1_stage(preds, &xs[(s + 1) & 1][0], b, (s + 1) * 2, l0, L, lane, wave);
        const float* xsb = &xs[s & 1][0];
        switch (wave) {
            case 0: k1_chunk<0>(xsb, targ, scl, wl, s * 2, lane, acc); break;
            case 1: k1_chunk<1>(xsb, targ, scl, wl, s * 2, lane, acc); break;
            case 2: k1_chunk<2>(xsb, targ, scl, wl, s * 2, lane, acc); break;
            default: k1_chunk<3>(xsb, targ, scl, wl, s * 2, lane, acc); break;
        }
    }

    // ---- acc -> S_lds, XOR-swizzled (row stride 128 B would be a 16-way
    // bank conflict on the b128 fragment reads; XOR of row&7 into bits[3:5]
    // of the short index spreads rows over 8 slots, residual 2-way = free)
#pragma unroll
    for (int r = 0; r < 34; ++r) {
        const int R = 34 * wave + r;
        sld[R * 64 + (lane ^ ((R & 7) << 3))] = f2bf(acc[r]);
    }
    __syncthreads();                              // cross-wave: tiles mix writers

    const int ntile = (wave == 3) ? 3 : 2;        // wave3 also owns tile 8
    f32x4 pacc[3][2];
#pragma unroll
    for (int ti = 0; ti < 3; ++ti)
#pragma unroll
        for (int pt = 0; pt < 2; ++pt)
            pacc[ti][pt] = (f32x4){0.f, 0.f, 0.f, 0.f};

    // ---- MFMA: pacc += S_tile x mask^T (layouts mirrored from verified k2)
#pragma unroll
    for (int ks = 0; ks < 2; ++ks) {
        bf16x8 bfr[2];
#pragma unroll
        for (int pt = 0; pt < 2; ++pt) {
            // B-frag: p = pt*16+(lane&15), 8 contig l; 0/1 -> bf16 = hi16
            const float* mp = masks + (size_t)(pt * 16 + (lane & 15)) * L
                            + l0 + ks * 32 + (lane >> 4) * 8;
            u32x4 m0 = *(const u32x4*)mp;
            u32x4 m1 = *(const u32x4*)(mp + 4);
            union { unsigned int u[4]; bf16x8 v; } bb;
            bb.u[0] = __builtin_amdgcn_perm(m0.y, m0.x, 0x07060302);
            bb.u[1] = __builtin_amdgcn_perm(m0.w, m0.z, 0x07060302);
            bb.u[2] = __builtin_amdgcn_perm(m1.y, m1.x, 0x07060302);
            bb.u[3] = __builtin_amdgcn_perm(m1.w, m1.z, 0x07060302);
            bfr[pt] = bb.v;
        }
#pragma unroll
        for (int ti = 0; ti < 3; ++ti) {
            if (ti >= ntile) continue;            // wave-uniform
            const int tile = (ti == 2) ? 8 : (wave + ti * 4);
            const bf16x8 a = *(const bf16x8*)&sld[
                (tile * 16 + (lane & 15)) * 64 +
                ((ks * 32 + (lane >> 4) * 8) ^ ((lane & 7) << 3))];
            pacc[ti][0] = __builtin_amdgcn_mfma_f32_16x16x32_bf16(
                a, bfr[0], pacc[ti][0], 0, 0, 0);
            pacc[ti][1] = __builtin_amdgcn_mfma_f32_16x16x32_bf16(
                a, bfr[1], pacc[ti][1], 0, 0, 0);
        }
    }

    // ---- store partial D2 for this (pb, b): [136][32] f32 -----------------
    float* P = partial + (size_t)(pb * 2 + b) * (NROWB * PMASK);
#pragma unroll
    for (int ti = 0; ti < 3; ++ti) {
        if (ti >= ntile) continue;
        const int tile = (ti == 2) ? 8 : (wave + ti * 4);
#pragma unroll
        for (int pt = 0; pt < 2; ++pt)
#pragma unroll
            for (int reg = 0; reg < 4; ++reg) {
                const int row = tile * 16 + (lane >> 4) * 4 + reg;
                if (row < NROWB)                  // drop pad rows 136..143
                    P[row * 32 + pt * 16 + (lane & 15)] = pacc[ti][pt][reg];
            }
    }
}

// -------- k3a: parallel pb-group sum: 34 x 30 blocks, 21 pb each -----------
__global__ __launch_bounds__(256, 2)
void k3a_reduce(const float* __restrict__ P, float* __restrict__ P2)
{
    const int t = (int)threadIdx.x;
    const int e = (int)blockIdx.x * 256 + t;      // 0..8703 = b*4352+row*32+p
    const int spl = (int)blockIdx.y;              // 0..29

    const float* p = P + (size_t)(spl * QPB) * PBSTRIDE + e;
    float a0 = 0.f, a1 = 0.f, a2 = 0.f;
#pragma unroll
    for (int q = 0; q < QPB; q += 3) {            // 21 = 7*3, all independent
        a0 += p[(size_t)(q    ) * PBSTRIDE];
        a1 += p[(size_t)(q + 1) * PBSTRIDE];
        a2 += p[(size_t)(q + 2) * PBSTRIDE];
    }
    P2[(size_t)spl * NE + e] = (a0 + a1) + a2;
}

// -------- k3b: final 30-sum (L2-resident), sqrt, weighted reduce, atomic ---
__global__ __launch_bounds__(256, 2)
void k3b_finalize(const float* __restrict__ P2, const int* __restrict__ beta_p,
                  float* __restrict__ out)
{
    const int t = (int)threadIdx.x;
    const int e = (int)blockIdx.x * 256 + t;      // 0..8703

    float a0 = 0.f, a1 = 0.f, a2 = 0.f;
#pragma unroll
    for (int q = 0; q < SPLIT; q += 3) {          // 30 independent loads
        a0 += P2[(size_t)(q    ) * NE + e];
        a1 += P2[(size_t)(q + 1) * NE + e];
        a2 += P2[(size_t)(q + 2) * NE + e];
    }
    float d2 = fmaxf((a0 + a1) + a2, 0.0f);
    float beta = (float)beta_p[0];
    float d = (beta == 1.0f) ? sqrtf(d2) : powf(d2, 0.5f * beta);

    const float wa = 1.0f / (float)(BS * M);
    const float wb = -1.0f / (float)(BS * M * (M - 1));
    const int row_g = e >> 5;                     // b*136 + row
    const int local = row_g % NROWB;
    float sum = ((local < M) ? wa : wb) * d;

    const int lane = t & 63, wv = t >> 6;
#pragma unroll
    for (int off = 32; off > 0; off >>= 1)
        sum += __shfl_down(sum, off, 64);
    __shared__ float red[4];
    if (lane == 0) red[wv] = sum;
    __syncthreads();
    if (t == 0)
        atomicAdd(out, red[0] + red[1] + red[2] + red[3]);
}

extern "C" void kernel_launch(void* const* d_in, const int* in_sizes, int n_in,
                              void* d_out, int out_size, void* d_ws, size_t ws_size,
                              hipStream_t stream)
{
    const float* preds   = (const float*)d_in[0];
    const float* target  = (const float*)d_in[1];
    const float* weights = (const float*)d_in[2];
    const float* scale   = (const float*)d_in[3];
    const float* masks   = (const float*)d_in[4];
    const int*   beta    = (const int*)d_in[5];
    float* out = (float*)d_out;

    int L = in_sizes[2];   // 40320 = NPB*64

    float* partial = (float*)d_ws;                // 630*2*136*32 f32 = 21.9 MB
    size_t p_bytes = (size_t)NPB * 2 * NROWB * PMASK * sizeof(float);
    float* partial2 = (float*)((char*)d_ws + ((p_bytes + 255) & ~(size_t)255));
                                                  // 30*8704 f32 = 1.04 MB

    dim3 g1(NPB, BS);                             // 630 x 2 = 1260 blocks
    k1_fused<<<g1, 256, 0, stream>>>(preds, target, weights, scale, masks,
                                     partial, out, L);

    dim3 g3a(NE / 256, SPLIT);                    // 34 x 30
    k3a_reduce<<<g3a, 256, 0, stream>>>(partial, partial2);

    k3b_finalize<<<NE / 256, 256, 0, stream>>>(partial2, beta, out);
}